// Round 9
// baseline (52.205 us; speedup 1.0000x reference)
//
#include <hip/hip_runtime.h>
#include <hip/hip_bf16.h>

typedef __attribute__((ext_vector_type(4))) float f32x4;
typedef __attribute__((ext_vector_type(4))) int i32x4;

#define M_DIM 256
#define N_DIM 16384
#define K_DIM 2048
#define BN 64
#define BK 64
#define NKT 32              // K tiles of 64
#define TEMP_INV 20.0f
#define FSCALE 16.0f        // fp8 pre-scale; logits = acc * TEMP_INV/(FSCALE^2)
#define OUTSCALE (TEMP_INV / (FSCALE * FSCALE))
#define SPECIAL 5554
#define IGNORE_IDX 1023

__device__ __forceinline__ void gload_lds16(const void* g, void* l) {
  __builtin_amdgcn_global_load_lds((const __attribute__((address_space(1))) void*)g,
                                   (__attribute__((address_space(3))) void*)l, 16, 0, 0);
}

// inputs f32 [256][2048] -> fp8(e4m3, x16) image, pre-swizzled for linear
// global_load_lds. Tile kt (32): 1024 chunks of 16B. LDS slot c (byte c*16)
// = (row = c>>2, slot s = (c&3) ^ ((row>>1)&3)) covering A[row][kt*64+s*16..+16].
__global__ __launch_bounds__(256) void convA(const float* __restrict__ A,
                                             int* __restrict__ Aimg) {
  int fid = blockIdx.x * 256 + threadIdx.x;   // 0..32767 chunks
  int kt = fid >> 10;
  int c = fid & 1023;
  int row = c >> 2;
  int s = (c & 3) ^ ((row >> 1) & 3);
  const float* src = A + (size_t)row * K_DIM + kt * BK + s * 16;
  i32x4 out;
#pragma unroll
  for (int j = 0; j < 4; ++j) {
    float4 v = *(const float4*)(src + j * 4);
    int d = __builtin_amdgcn_cvt_pk_fp8_f32(v.x * FSCALE, v.y * FSCALE, 0, false);
    d = __builtin_amdgcn_cvt_pk_fp8_f32(v.z * FSCALE, v.w * FSCALE, d, true);
    out[j] = d;
  }
  *reinterpret_cast<i32x4*>(Aimg + (size_t)fid * 4) = out;
}

// Fused fp8 GEMM + exp-rowsum + target capture. BM=256 (B read ONCE),
// BN=64, BK=64, 512 threads = 8 waves (wave tile 64x32), grid 256 = 1/CU.
// R2-proven compiler-scheduled __syncthreads pipeline (no manual vmcnt).
__global__ __launch_bounds__(512, 1) void gemm_fused(
    const int* __restrict__ Aimg, const float* __restrict__ B,
    const int* __restrict__ targets,
    float* __restrict__ partial,    // [256 bn][256 rows]
    float* __restrict__ targ) {     // [256]
  __shared__ __align__(16) int Al[2][M_DIM * 16];  // 256 rows x 64B fp8 = 16 KB/buf
  __shared__ __align__(16) int Bl[2][BN * 18];     // 64 rows x 72B (pitch-pad) /buf
  __shared__ int tcs[M_DIM];
  __shared__ float rsum[M_DIM][2];

  int bn = blockIdx.x;            // 0..255
  int tid = threadIdx.x;
  int wave = tid >> 6;
  int lane = tid & 63;
  int rl = lane & 15;
  int kq = lane >> 4;             // 0..3
  int wm = wave >> 1;             // 0..3 -> rows wm*64..+63
  int wn = wave & 1;              // 0..1 -> cols wn*32..+31

  if (tid < M_DIM) {
    int tt = targets[tid] - 1;
    if (tt == SPECIAL) tt = IGNORE_IDX;
    tcs[tid] = tt < 0 ? 0 : (tt > N_DIM - 1 ? N_DIM - 1 : tt);
  }

  // B staging: thread covers row = tid>>3 (0..63), quad = tid&7; two float4
  // at k = quad*4 and quad*4+32 (8 threads x 16B = 128B contiguous per row).
  const float* bbase = B + ((size_t)bn * BN + (tid >> 3)) * K_DIM + (tid & 7) * 4;

  f32x4 acc[4][2];
#pragma unroll
  for (int m = 0; m < 4; ++m)
#pragma unroll
    for (int n = 0; n < 2; ++n) acc[m][n] = f32x4{0.f, 0.f, 0.f, 0.f};

  float4 S0[2], S1[2];  // B reg sets, static indices only

#define ADMA(t, buf)                                                          \
  { gload_lds16(Aimg + (((size_t)(t) * 1024 + tid) << 2),                     \
                (char*)&Al[buf][0] + (size_t)tid * 16);                       \
    gload_lds16(Aimg + (((size_t)(t) * 1024 + 512 + tid) << 2),               \
                (char*)&Al[buf][0] + (size_t)(512 + tid) * 16); }

#define BGLB(t, R)                                                            \
  { const float* _p = bbase + (size_t)(t) * BK;                               \
    R[0] = *(const float4*)_p;                                                \
    R[1] = *(const float4*)(_p + 32); }

#define CVTW(R, buf)                                                          \
  { int _r = tid >> 3, _c = tid & 7;                                          \
    int _d0 = __builtin_amdgcn_cvt_pk_fp8_f32(R[0].x * FSCALE, R[0].y * FSCALE, 0, false); \
    _d0 = __builtin_amdgcn_cvt_pk_fp8_f32(R[0].z * FSCALE, R[0].w * FSCALE, _d0, true);    \
    int _d1 = __builtin_amdgcn_cvt_pk_fp8_f32(R[1].x * FSCALE, R[1].y * FSCALE, 0, false); \
    _d1 = __builtin_amdgcn_cvt_pk_fp8_f32(R[1].z * FSCALE, R[1].w * FSCALE, _d1, true);    \
    Bl[buf][_r * 18 + _c] = _d0;                                              \
    Bl[buf][_r * 18 + 8 + _c] = _d1; }

#define COMPUTE(par)                                                          \
  { const long* _al = (const long*)&Al[par][0];                               \
    const long* _bl = (const long*)&Bl[par][0];                               \
    _Pragma("unroll") for (int _kk = 0; _kk < 2; ++_kk) {                     \
      long _af[4], _bf[2];                                                    \
      int _s = _kk * 2 + (kq >> 1);                                           \
      _Pragma("unroll") for (int _m = 0; _m < 4; ++_m) {                      \
        int _row = wm * 64 + _m * 16 + rl;                                    \
        int _sx = _s ^ ((_row >> 1) & 3);                                     \
        _af[_m] = _al[((_row << 2) + _sx) * 2 + (kq & 1)];                    \
      }                                                                       \
      _Pragma("unroll") for (int _n = 0; _n < 2; ++_n) {                      \
        int _row = wn * 32 + _n * 16 + rl;                                    \
        _bf[_n] = _bl[_row * 9 + _kk * 4 + kq];                               \
      }                                                                       \
      _Pragma("unroll") for (int _m = 0; _m < 4; ++_m)                        \
          _Pragma("unroll") for (int _n = 0; _n < 2; ++_n)                    \
              acc[_m][_n] = __builtin_amdgcn_mfma_f32_16x16x32_fp8_fp8(       \
                  _af[_m], _bf[_n], acc[_m][_n], 0, 0, 0);                    \
    } }

  // Prologue: A(0) dma -> buf0, B(0)->S0, B(1)->S1, publish B(0) -> buf0.
  ADMA(0, 0);
  BGLB(0, S0);
  BGLB(1, S1);
  CVTW(S0, 0);
  __syncthreads();

  // Body(kt): ADMA(kt+1) into other buf, prefetch B(kt+2) into freed reg set,
  // compute buf[kt&1], publish B(kt+1), barrier. Compiler schedules waits.
  for (int ktb = 0; ktb < NKT; ktb += 2) {
    {  // even kt
      int kt = ktb;
      if (kt + 1 < NKT) ADMA(kt + 1, 1);
      if (kt + 2 < NKT) BGLB(kt + 2, S0);
      COMPUTE(0);
      if (kt + 1 < NKT) {
        CVTW(S1, 1);
        __syncthreads();
      }
    }
    {  // odd kt
      int kt = ktb + 1;
      if (kt + 1 < NKT) ADMA(kt + 1, 0);
      if (kt + 2 < NKT) BGLB(kt + 3 <= NKT ? kt + 2 : 0, S1);
      COMPUTE(1);
      if (kt + 1 < NKT) {
        CVTW(S0, 0);
        __syncthreads();
      }
    }
  }

  // ---- fused epilogue: exp + per-row reduce + target capture ----
  int colbase = bn * BN + wn * 32 + rl;
#pragma unroll
  for (int m = 0; m < 4; ++m) {
#pragma unroll
    for (int r = 0; r < 4; ++r) {
      int row = wm * 64 + m * 16 + kq * 4 + r;   // 0..255
      int tc = tcs[row];
      float s = 0.f;
#pragma unroll
      for (int n = 0; n < 2; ++n) {
        float logit = acc[m][n][r] * OUTSCALE;
        if (colbase + n * 16 == tc) targ[row] = logit;
        s += __expf(logit);
      }
#pragma unroll
      for (int msk = 1; msk < 16; msk <<= 1) s += __shfl_xor(s, msk, 64);
      if (rl == 0) rsum[row][wn] = s;
    }
  }
  __syncthreads();
  if (tid < M_DIM) {
    partial[(size_t)bn * M_DIM + tid] = rsum[tid][0] + rsum[tid][1];
  }
#undef ADMA
#undef BGLB
#undef CVTW
#undef COMPUTE
}

__global__ __launch_bounds__(256) void finalize(
    const float* __restrict__ partial, const float* __restrict__ targ,
    const int* __restrict__ targets, float* __restrict__ out) {
  int r = threadIdx.x;  // 256 rows
  float s = 0.f;
  for (int j = 0; j < 256; ++j) s += partial[(size_t)j * M_DIM + r];
  int t = targets[r] - 1;
  if (t == SPECIAL) t = IGNORE_IDX;
  bool valid = (t >= 0) && (t != IGNORE_IDX);
  float nl = logf(s) - targ[r];
  float sv = valid ? nl : 0.0f;
  float cv = valid ? 1.0f : 0.0f;
#pragma unroll
  for (int m = 1; m < 64; m <<= 1) {
    sv += __shfl_xor(sv, m, 64);
    cv += __shfl_xor(cv, m, 64);
  }
  __shared__ float ss[4], cc[4];
  int wid = r >> 6, lane = r & 63;
  if (lane == 0) { ss[wid] = sv; cc[wid] = cv; }
  __syncthreads();
  if (r == 0) {
    float S = ss[0] + ss[1] + ss[2] + ss[3];
    float C = cc[0] + cc[1] + cc[2] + cc[3];
    out[0] = S / fmaxf(C, 1.0f);
  }
}

extern "C" void kernel_launch(void* const* d_in, const int* in_sizes, int n_in,
                              void* d_out, int out_size, void* d_ws, size_t ws_size,
                              hipStream_t stream) {
  const float* inputs   = (const float*)d_in[0];  // [256, 2048]
  const int*   targets  = (const int*)d_in[1];    // [256]
  const float* features = (const float*)d_in[2];  // [16384, 2048]
  float* out = (float*)d_out;

  int*   Aimg    = (int*)d_ws;                          // 512 KB fp8 image
  float* partial = (float*)((char*)d_ws + (1 << 20));   // [256][256] f32 = 256 KB
  float* targ    = partial + 256 * M_DIM;               // [256] f32

  convA<<<dim3(128), dim3(256), 0, stream>>>(inputs, Aimg);
  gemm_fused<<<dim3(256), dim3(512), 0, stream>>>(Aimg, features, targets, partial, targ);
  finalize<<<dim3(1), dim3(256), 0, stream>>>(partial, targ, targets, out);
}